// Round 6
// baseline (295.521 us; speedup 1.0000x reference)
//
#include <hip/hip_runtime.h>

#define NN 20000
#define NNP 20096       // padded rows: 314*64
#define NEIGH 12
#define NCRYS 20
#define MT2 1256        // padded M row-tiles of 16
#define NSUB 16         // pooled partial-sum split

typedef __bf16 bf16x8 __attribute__((ext_vector_type(8)));
typedef float f32x4 __attribute__((ext_vector_type(4)));

// ============================================================
// pack: W[k][n] -> bf16 MFMA-B frag layout Wp[kt][nt][k8][ni][j]
// ============================================================
__device__ __forceinline__ void pack_one(const float* Wrel, const float* Wroot,
                                         __bf16* Wp, int K, int idx) {
    int k = idx >> 8, n = idx & 255;
    int r = n >> 6, h = n & 63;
    float v = (r < 3) ? Wrel[((size_t)r * K + k) * 64 + h] : Wroot[(size_t)k * 64 + h];
    int kt = k >> 5, k8 = (k >> 3) & 3, j = k & 7, nt = n >> 4, ni = n & 15;
    Wp[((((size_t)kt * 16 + nt) * 4 + k8) * 16 + ni) * 8 + j] = (__bf16)v;
}

// ============================================================
// setup: build_adj (938) + pack (256, strided) + transpose (628)
// ============================================================
__global__ __launch_bounds__(256) void setup_kernel(
    const int* __restrict__ species, const int* __restrict__ nbr,
    int* __restrict__ adj, int* __restrict__ deg,
    const float* __restrict__ W1b_rel, const float* __restrict__ W1b_root,
    const float* __restrict__ W1a_rel, const float* __restrict__ W1a_root,
    const float* __restrict__ W2b_rel, const float* __restrict__ W2b_root,
    const float* __restrict__ W2a_rel, const float* __restrict__ W2a_root,
    __bf16* __restrict__ Wp1b, __bf16* __restrict__ Wp1a,
    __bf16* __restrict__ Wp2b, __bf16* __restrict__ Wp2a,
    const float* __restrict__ bond, const float* __restrict__ angle,
    float* __restrict__ bondT, float* __restrict__ angleT) {
    __shared__ float ls[64 * 145];
    const int bx = blockIdx.x, tid = threadIdx.x;
    if (bx < 938) {
        int e = bx * 256 + tid;
        if (e < NN * NEIGH) {
            int i = e / NEIGH;
            int d = nbr[e];
            int r = species[i] + species[d];
            int slot = atomicAdd(&deg[d], 1);
            if (slot < 64) adj[(size_t)d * 64 + slot] = i | (r << 28);
        }
    } else if (bx < 938 + 256) {
        const int S0 = 480 * 256, S1 = S0 + 2880 * 256, S2 = S1 + 64 * 256, S3 = S2 + 64 * 256;
        for (int idx = (bx - 938) * 256 + tid; idx < S3; idx += 256 * 256) {
            if (idx < S0)       pack_one(W1b_rel, W1b_root, Wp1b, 480, idx);
            else if (idx < S1)  pack_one(W1a_rel, W1a_root, Wp1a, 2880, idx - S0);
            else if (idx < S2)  pack_one(W2b_rel, W2b_root, Wp2b, 64, idx - S1);
            else                pack_one(W2a_rel, W2a_root, Wp2a, 64, idx - S2);
        }
    } else {
        int tb = bx - 1194;
        if (tb < 314) {
            int m0 = tb * 64;
            for (int idx = tid; idx < 64 * 144; idx += 256) {
                int mm = idx / 144, j = idx - mm * 144;
                int m = m0 + mm;
                ls[mm * 145 + j] = (m < NN) ? angle[(size_t)m * 144 + j] : 0.f;
            }
            __syncthreads();
            for (int idx = tid; idx < 144 * 64; idx += 256) {
                int j = idx >> 6, mm = idx & 63;
                angleT[(size_t)j * NNP + m0 + mm] = ls[mm * 145 + j];
            }
        } else {
            int m0 = (tb - 314) * 64;
            for (int idx = tid; idx < 64 * 12; idx += 256) {
                int mm = idx / 12, j = idx - mm * 12;
                int m = m0 + mm;
                ls[mm * 13 + j] = (m < NN) ? bond[(size_t)m * 12 + j] : 0.f;
            }
            __syncthreads();
            for (int idx = tid; idx < 12 * 64; idx += 256) {
                int j = idx >> 6, mm = idx & 63;
                bondT[(size_t)j * NNP + m0 + mm] = ls[mm * 13 + j];
            }
        }
    }
}

// ============================================================
// gemm1: 64x256 tile, A staged via gbf recurrence into LDS dbuf,
// B global->frag regs (packed layout = frag layout), depth-2 prefetch.
// Gaussian chain within 4-filter chunk: E_{s+1}=E_s*Q_s, Q_{s+1}=Q_s*C.
// Underflow-safe: if E_0 flushes, all true chunk values < e^-36 ~ 0.
// ============================================================
template <int MODE>  // 0: bond DIVN=40 gamma=25; 1: angle DIVN=20 gamma=100
__device__ __forceinline__ void gemm1_body(const float* __restrict__ xT,
                                           const __bf16* __restrict__ Wp,
                                           __bf16* __restrict__ Yh, int mb,
                                           __bf16* __restrict__ Al) {
    constexpr int KTOT = (MODE == 0) ? 480 : 2880;
    constexpr int NKT = KTOT / 32;
    constexpr int DIVN = (MODE == 0) ? 40 : 20;
    constexpr float F0 = (MODE == 0) ? 0.f : -1.f;
    constexpr float FS = (MODE == 0) ? (8.f / 39.f) : (2.f / 19.f);
    constexpr float NG2 = ((MODE == 0) ? -25.f : -100.f) * 1.44269504f;  // -gamma*log2e
    const float C  = __builtin_amdgcn_exp2f(2.f * NG2 * FS * FS);
    const float P1 = NG2 * FS * FS;
    const float P2 = -2.f * NG2 * FS;

    const int tid = threadIdx.x;
    const int lane = tid & 63, wv = tid >> 6;
    const int m0 = mb * 64;
    // staging role: tid -> (mt, k8s, mi)
    const int k8s = (tid >> 4) & 3;
    const int gm = m0 + ((tid >> 6) << 4) + (tid & 15);
    // frag role
    const int k8b = lane >> 4, nib = lane & 15;
    const bf16x8* Bg = (const bf16x8*)Wp;

    f32x4 acc[4][4] = {};
    bf16x8 bcur[4], bn1[4], bn2[4];
    float a1c0, a1c1;

    auto bload = [&](int kt, bf16x8* dst) {
#pragma unroll
        for (int j = 0; j < 4; ++j)
            dst[j] = Bg[(((size_t)kt * 16 + wv * 4 + j) * 4 + k8b) * 16 + nib];
    };
    auto aload = [&](int kt, float& a0, float& a1) {
        int kb = kt * 32 + k8s * 8;
        int jr0 = kb / DIVN;
        int jr1 = (kb + 4) / DIVN;
        a0 = xT[(size_t)jr0 * NNP + gm];
        a1 = xT[(size_t)jr1 * NNP + gm];
    };
    // 4-value gaussian chain
    auto gbf4 = [&](float a, float fstart, bf16x8& vals, int base) {
        float d0 = a - fstart;
        float e0 = __builtin_amdgcn_exp2f(NG2 * d0 * d0);
        float q0 = __builtin_amdgcn_exp2f(fmaf(P2, d0, P1));
        float e1 = e0 * q0;
        float q1 = q0 * C;
        float e2 = e1 * q1;
        float q2 = q1 * C;
        float e3 = e2 * q2;
        vals[base + 0] = (__bf16)e0;
        vals[base + 1] = (__bf16)e1;
        vals[base + 2] = (__bf16)e2;
        vals[base + 3] = (__bf16)e3;
    };
    auto stage = [&](int kt, float a0, float a1, __bf16* Ab) {
        int kb = kt * 32 + k8s * 8;
        int jr0 = kb / DIVN;
        int s0 = kb - jr0 * DIVN;
        int kb1 = kb + 4;
        int jr1 = kb1 / DIVN;
        int s1 = kb1 - jr1 * DIVN;
        bf16x8 vals;
        gbf4(a0, F0 + (float)s0 * FS, vals, 0);
        gbf4(a1, F0 + (float)s1 * FS, vals, 4);
        *(bf16x8*)&Ab[tid << 3] = vals;
    };

    // ---- prologue ----
    bload(0, bcur);
    bload(1, bn1);
    {
        float p0, p1;
        aload(0, p0, p1);
        stage(0, p0, p1, Al);
    }
    aload(1, a1c0, a1c1);
    __syncthreads();

    for (int kt = 0; kt < NKT; ++kt) {
        __bf16* Ab = Al + ((kt & 1) << 11);
        __bf16* An = Al + (((kt & 1) ^ 1) << 11);
        const int ktp2 = (kt + 2 < NKT) ? kt + 2 : NKT - 1;
        bload(ktp2, bn2);                // depth-2 B prefetch
        float an0, an1;
        aload(ktp2, an0, an1);           // depth-2 A prefetch
        // MFMA on current buffer
        bf16x8 af[4];
        const int fro = (k8b << 4) + nib;
#pragma unroll
        for (int t = 0; t < 4; ++t)
            af[t] = *(const bf16x8*)&Ab[((t << 6) + fro) << 3];
#pragma unroll
        for (int i = 0; i < 4; ++i)
#pragma unroll
            for (int j = 0; j < 4; ++j)
                acc[i][j] = __builtin_amdgcn_mfma_f32_16x16x32_bf16(af[i], bcur[j], acc[i][j], 0, 0, 0);
        if (kt + 1 < NKT)
            stage(kt + 1, a1c0, a1c1, An);
        __syncthreads();
#pragma unroll
        for (int j = 0; j < 4; ++j) { bcur[j] = bn1[j]; bn1[j] = bn2[j]; }
        a1c0 = an0; a1c1 = an1;
    }

    // ---- epilogue: C/D layout col=lane&15, row=(lane>>4)*4+reg; bf16 out ----
    const int mrow0 = m0 + ((lane >> 4) << 2);
    const int ncol = (wv << 6) + nib;
#pragma unroll
    for (int i = 0; i < 4; ++i)
#pragma unroll
        for (int j = 0; j < 4; ++j)
#pragma unroll
            for (int v = 0; v < 4; ++v) {
                int m = mrow0 + i * 16 + v;
                if (m < NN) Yh[(size_t)m * 256 + ncol + j * 16] = (__bf16)acc[i][j][v];
            }
}

__global__ __launch_bounds__(256) void mega_gemm1(const float* __restrict__ bondT,
                                                  const float* __restrict__ angleT,
                                                  const __bf16* __restrict__ Wp1b,
                                                  const __bf16* __restrict__ Wp1a,
                                                  __bf16* __restrict__ Yb, __bf16* __restrict__ Ya) {
    __shared__ __align__(16) __bf16 Al[2 * 2048];
    int bx = blockIdx.x;
    if (bx < 314) gemm1_body<1>(angleT, Wp1a, Ya, bx, Al);
    else          gemm1_body<0>(bondT, Wp1b, Yb, bx - 314, Al);
}

// ============================================================
// Dense layer-2 GEMM, both chains. K=64, A pre-packed bf16, bf16 out
// ============================================================
__global__ __launch_bounds__(256) void mega_gemm2(const __bf16* __restrict__ Hbp,
                                                  const __bf16* __restrict__ Hap,
                                                  const __bf16* __restrict__ Wp2b,
                                                  const __bf16* __restrict__ Wp2a,
                                                  __bf16* __restrict__ Yb, __bf16* __restrict__ Ya) {
    __shared__ __align__(16) __bf16 Al[4096];
    __shared__ __align__(16) __bf16 Bl[4096];
    const int ch = blockIdx.x & 1;
    const int mb = blockIdx.x >> 1;
    const int nb = blockIdx.y;
    const __bf16* Ap = ch ? Hap : Hbp;
    const __bf16* Wp = ch ? Wp2a : Wp2b;
    __bf16* Y = ch ? Ya : Yb;
    const int tid = threadIdx.x;
    const int lane = tid & 63, wv = tid >> 6;
    const int m0 = mb * 128;
    const int rw = wv & 1, cw = wv >> 1;
    f32x4 acc[4][4] = {};
#pragma unroll
    for (int kt = 0; kt < 2; ++kt) {
        __syncthreads();
        {
            const float4* src = (const float4*)(Wp + (((size_t)kt * 16 + nb * 8) << 9));
            float4* dst = (float4*)Bl;
            float4 v0 = src[tid], v1 = src[tid + 256];
            dst[tid] = v0;
            dst[tid + 256] = v1;
        }
        {
            const float4* src = (const float4*)(Ap + (((size_t)kt * MT2 + mb * 8) << 9));
            float4* dst = (float4*)Al;
            float4 v0 = src[tid], v1 = src[tid + 256];
            dst[tid] = v0;
            dst[tid + 256] = v1;
        }
        __syncthreads();
        bf16x8 af[4], bfr[4];
        int fro = ((lane >> 4) << 4) + (lane & 15);
#pragma unroll
        for (int t4 = 0; t4 < 4; ++t4) {
            af[t4] = *(const bf16x8*)&Al[((((rw * 4 + t4) << 6) + fro) << 3)];
            bfr[t4] = *(const bf16x8*)&Bl[((((cw * 4 + t4) << 6) + fro) << 3)];
        }
#pragma unroll
        for (int i = 0; i < 4; ++i)
#pragma unroll
            for (int j = 0; j < 4; ++j)
                acc[i][j] = __builtin_amdgcn_mfma_f32_16x16x32_bf16(af[i], bfr[j], acc[i][j], 0, 0, 0);
    }
    const int n0 = nb * 128 + cw * 64;
    const int mrow0 = m0 + rw * 64 + ((lane >> 4) << 2);
    const int ncol = n0 + (lane & 15);
#pragma unroll
    for (int i = 0; i < 4; ++i)
#pragma unroll
        for (int j = 0; j < 4; ++j)
#pragma unroll
            for (int v = 0; v < 4; ++v) {
                int m = mrow0 + i * 16 + v;
                if (m < NN) Y[(size_t)m * 256 + ncol + j * 16] = (__bf16)acc[i][j][v];
            }
}

// ============================================================
// agg core on bf16 Y
// ============================================================
__device__ __forceinline__ float agg_node(const __bf16* __restrict__ Y,
                                          const int* __restrict__ adj,
                                          const int* __restrict__ deg,
                                          const float* __restrict__ bias,
                                          int node, int h) {
    int dg = min(deg[node], 64);
    int e = adj[(size_t)node * 64 + h];
    bool val = h < dg;
    int r = e >> 28;
    unsigned long long bl0 = __ballot(val && r == 0);
    unsigned long long bl1 = __ballot(val && r == 1);
    unsigned long long bl2 = __ballot(val && r == 2);
    int c0 = __popcll(bl0), c1 = __popcll(bl1), c2 = __popcll(bl2);
    float s0 = 0.f, s1 = 0.f, s2 = 0.f;
    for (int k = 0; k < dg; k += 4) {
        float v[4];
        int rr[4];
#pragma unroll
        for (int i = 0; i < 4; ++i) {
            int kk = k + i;
            int ek = __shfl(e, kk);
            int src = ek & 0x0FFFFFFF;
            rr[i] = ek >> 28;
            v[i] = (kk < dg) ? (float)Y[(size_t)src * 256 + rr[i] * 64 + h] : 0.f;
        }
#pragma unroll
        for (int i = 0; i < 4; ++i) {
            if (k + i < dg) {
                if (rr[i] == 0) s0 += v[i];
                else if (rr[i] == 1) s1 += v[i];
                else s2 += v[i];
            }
        }
    }
    float o = (float)Y[(size_t)node * 256 + 192 + h] + bias[h] +
              s0 / fmaxf((float)c0, 1.f) + s1 / fmaxf((float)c1, 1.f) +
              s2 / fmaxf((float)c2, 1.f);
    return fmaxf(o, 0.f);
}

// layer-1 agg -> bf16 packed-A frag layout (feeds mega_gemm2)
__global__ __launch_bounds__(256) void agg_packed(const __bf16* __restrict__ Yb,
                                                  const __bf16* __restrict__ Ya,
                                                  const int* __restrict__ adj,
                                                  const int* __restrict__ deg,
                                                  const float* __restrict__ biasb,
                                                  const float* __restrict__ biasa,
                                                  __bf16* __restrict__ outb,
                                                  __bf16* __restrict__ outa) {
    const __bf16* Y = blockIdx.y ? Ya : Yb;
    const float* bias = blockIdx.y ? biasa : biasb;
    __bf16* outp = blockIdx.y ? outa : outb;
    int node = blockIdx.x * 4 + (threadIdx.x >> 6);
    int h = threadIdx.x & 63;
    float o = (node < NN) ? agg_node(Y, adj, deg, bias, node, h) : 0.f;
    int mt = node >> 4, mi = node & 15;
    int ktt = h >> 5, k8 = (h >> 3) & 3, j = h & 7;
    outp[((((size_t)ktt * MT2 + mt) * 4 + k8) * 16 + mi) * 8 + j] = (__bf16)o;
}

// layer-2 agg fused with crystal pooling
__global__ __launch_bounds__(256) void agg_pool(const __bf16* __restrict__ Yb,
                                                const __bf16* __restrict__ Ya,
                                                const int* __restrict__ adj,
                                                const int* __restrict__ deg,
                                                const float* __restrict__ biasb,
                                                const float* __restrict__ biasa,
                                                const int* __restrict__ crys,
                                                float* __restrict__ pooled) {
    const __bf16* Y = blockIdx.y ? Ya : Yb;
    const float* bias = blockIdx.y ? biasa : biasb;
    const int base = blockIdx.y ? 64 : 0;
    int node = blockIdx.x * 4 + (threadIdx.x >> 6);
    int h = threadIdx.x & 63;
    if (node >= NN) return;
    float o = agg_node(Y, adj, deg, bias, node, h);
    int c = 0;
#pragma unroll
    for (int t = 1; t < NCRYS; ++t) c += (node >= crys[t * 2]) ? 1 : 0;
    int sub = blockIdx.x & (NSUB - 1);
    atomicAdd(&pooled[((size_t)c * NSUB + sub) * 128 + base + h], o);
}

// ============================================================
// final: reduce partials, divide by count, FC
// ============================================================
__global__ void final2(const float* __restrict__ pooled, const int* __restrict__ crys,
                       const float* __restrict__ fcW, const float* __restrict__ fcb,
                       float* __restrict__ out) {
    int c = blockIdx.x >> 1, o = blockIdx.x & 1;
    int l = threadIdx.x;  // 0..63
    float cnt = (float)(crys[c * 2 + 1] - crys[c * 2]);
    float sb = 0.f, sa = 0.f;
    for (int s = 0; s < NSUB; ++s) {
        sb += pooled[((size_t)c * NSUB + s) * 128 + l];
        sa += pooled[((size_t)c * NSUB + s) * 128 + 64 + l];
    }
    float a = sb * fcW[l * 2 + o] + sa * fcW[(64 + l) * 2 + o];
    for (int s = 32; s > 0; s >>= 1) a += __shfl_down(a, s);
    if (l == 0) out[c * 2 + o] = a / cnt + fcb[o];
}

extern "C" void kernel_launch(void* const* d_in, const int* in_sizes, int n_in,
                              void* d_out, int out_size, void* d_ws, size_t ws_size,
                              hipStream_t stream) {
    const float* bond    = (const float*)d_in[0];
    const float* angle   = (const float*)d_in[1];
    const int*   species = (const int*)d_in[2];
    const int*   nbr     = (const int*)d_in[3];
    const int*   crys    = (const int*)d_in[4];
    const float* W1b_rel = (const float*)d_in[5];
    const float* W1b_root= (const float*)d_in[6];
    const float* b1b     = (const float*)d_in[7];
    const float* W1a_rel = (const float*)d_in[8];
    const float* W1a_root= (const float*)d_in[9];
    const float* b1a     = (const float*)d_in[10];
    const float* W2b_rel = (const float*)d_in[11];
    const float* W2b_root= (const float*)d_in[12];
    const float* b2b     = (const float*)d_in[13];
    const float* W2a_rel = (const float*)d_in[14];
    const float* W2a_root= (const float*)d_in[15];
    const float* b2a     = (const float*)d_in[16];
    const float* fcW     = (const float*)d_in[17];
    const float* fcb     = (const float*)d_in[18];
    float* out = (float*)d_out;

    char* ws = (char*)d_ws;
    size_t off = 0;
    auto alloc = [&](size_t bytes) {
        char* p = ws + off;
        off = (off + bytes + 255) & ~(size_t)255;
        return p;
    };
    __bf16* Wp1b = (__bf16*)alloc((size_t)480 * 256 * 2);
    __bf16* Wp1a = (__bf16*)alloc((size_t)2880 * 256 * 2);
    __bf16* Wp2b = (__bf16*)alloc((size_t)64 * 256 * 2);
    __bf16* Wp2a = (__bf16*)alloc((size_t)64 * 256 * 2);
    float*  bondT = (float*)alloc((size_t)12 * NNP * 4);
    float*  angleT= (float*)alloc((size_t)144 * NNP * 4);
    __bf16* Yb   = (__bf16*)alloc((size_t)NN * 256 * 2);
    __bf16* Ya   = (__bf16*)alloc((size_t)NN * 256 * 2);
    __bf16* Hbp  = (__bf16*)alloc((size_t)2 * MT2 * 512 * 2);
    __bf16* Hap  = (__bf16*)alloc((size_t)2 * MT2 * 512 * 2);
    int*    adj  = (int*)alloc((size_t)NN * 64 * 4);
    int*    deg  = (int*)alloc((size_t)NN * 4);
    float*  pooled = (float*)alloc((size_t)NCRYS * NSUB * 128 * 4);

    hipMemsetAsync(deg, 0, (size_t)NN * 4, stream);
    hipMemsetAsync(pooled, 0, (size_t)NCRYS * NSUB * 128 * 4, stream);

    setup_kernel<<<1822, 256, 0, stream>>>(species, nbr, adj, deg,
                                           W1b_rel, W1b_root, W1a_rel, W1a_root,
                                           W2b_rel, W2b_root, W2a_rel, W2a_root,
                                           Wp1b, Wp1a, Wp2b, Wp2a,
                                           bond, angle, bondT, angleT);

    mega_gemm1<<<628, 256, 0, stream>>>(bondT, angleT, Wp1b, Wp1a, Yb, Ya);
    agg_packed<<<dim3(5024, 2), 256, 0, stream>>>(Yb, Ya, adj, deg, b1b, b1a, Hbp, Hap);
    mega_gemm2<<<dim3(314, 2), 256, 0, stream>>>(Hbp, Hap, Wp2b, Wp2a, Yb, Ya);
    agg_pool<<<dim3(5000, 2), 256, 0, stream>>>(Yb, Ya, adj, deg, b2b, b2a, crys, pooled);
    final2<<<NCRYS * 2, 64, 0, stream>>>(pooled, crys, fcW, fcb, out);
}

// Round 7
// 256.857 us; speedup vs baseline: 1.1505x; 1.1505x over previous
//
#include <hip/hip_runtime.h>

#define NN 20000
#define NNP 20096       // padded rows: 314*64
#define NEIGH 12
#define NCRYS 20
#define MT2 1256        // padded M row-tiles of 16
#define NSUB 16         // pooled partial-sum split

typedef __bf16 bf16x8 __attribute__((ext_vector_type(8)));
typedef __bf16 bf16x4 __attribute__((ext_vector_type(4)));
typedef float f32x4 __attribute__((ext_vector_type(4)));

// ============================================================
// pack: W[k][n] -> bf16 MFMA-B frag layout Wp[kt][nt][k8][ni][j]
// ============================================================
__device__ __forceinline__ void pack_one(const float* Wrel, const float* Wroot,
                                         __bf16* Wp, int K, int idx) {
    int k = idx >> 8, n = idx & 255;
    int r = n >> 6, h = n & 63;
    float v = (r < 3) ? Wrel[((size_t)r * K + k) * 64 + h] : Wroot[(size_t)k * 64 + h];
    int kt = k >> 5, k8 = (k >> 3) & 3, j = k & 7, nt = n >> 4, ni = n & 15;
    Wp[((((size_t)kt * 16 + nt) * 4 + k8) * 16 + ni) * 8 + j] = (__bf16)v;
}

// ============================================================
// setup: build_adj (938) + pack (256, strided) + transpose (628)
// ============================================================
__global__ __launch_bounds__(256) void setup_kernel(
    const int* __restrict__ species, const int* __restrict__ nbr,
    int* __restrict__ adj, int* __restrict__ deg,
    const float* __restrict__ W1b_rel, const float* __restrict__ W1b_root,
    const float* __restrict__ W1a_rel, const float* __restrict__ W1a_root,
    const float* __restrict__ W2b_rel, const float* __restrict__ W2b_root,
    const float* __restrict__ W2a_rel, const float* __restrict__ W2a_root,
    __bf16* __restrict__ Wp1b, __bf16* __restrict__ Wp1a,
    __bf16* __restrict__ Wp2b, __bf16* __restrict__ Wp2a,
    const float* __restrict__ bond, const float* __restrict__ angle,
    float* __restrict__ bondT, float* __restrict__ angleT) {
    __shared__ float ls[64 * 145];
    const int bx = blockIdx.x, tid = threadIdx.x;
    if (bx < 938) {
        int e = bx * 256 + tid;
        if (e < NN * NEIGH) {
            int i = e / NEIGH;
            int d = nbr[e];
            int r = species[i] + species[d];
            int slot = atomicAdd(&deg[d], 1);
            if (slot < 64) adj[(size_t)d * 64 + slot] = i | (r << 28);
        }
    } else if (bx < 938 + 256) {
        const int S0 = 480 * 256, S1 = S0 + 2880 * 256, S2 = S1 + 64 * 256, S3 = S2 + 64 * 256;
        for (int idx = (bx - 938) * 256 + tid; idx < S3; idx += 256 * 256) {
            if (idx < S0)       pack_one(W1b_rel, W1b_root, Wp1b, 480, idx);
            else if (idx < S1)  pack_one(W1a_rel, W1a_root, Wp1a, 2880, idx - S0);
            else if (idx < S2)  pack_one(W2b_rel, W2b_root, Wp2b, 64, idx - S1);
            else                pack_one(W2a_rel, W2a_root, Wp2a, 64, idx - S2);
        }
    } else {
        int tb = bx - 1194;
        if (tb < 314) {
            int m0 = tb * 64;
            for (int idx = tid; idx < 64 * 144; idx += 256) {
                int mm = idx / 144, j = idx - mm * 144;
                int m = m0 + mm;
                ls[mm * 145 + j] = (m < NN) ? angle[(size_t)m * 144 + j] : 0.f;
            }
            __syncthreads();
            for (int idx = tid; idx < 144 * 64; idx += 256) {
                int j = idx >> 6, mm = idx & 63;
                angleT[(size_t)j * NNP + m0 + mm] = ls[mm * 145 + j];
            }
        } else {
            int m0 = (tb - 314) * 64;
            for (int idx = tid; idx < 64 * 12; idx += 256) {
                int mm = idx / 12, j = idx - mm * 12;
                int m = m0 + mm;
                ls[mm * 13 + j] = (m < NN) ? bond[(size_t)m * 12 + j] : 0.f;
            }
            __syncthreads();
            for (int idx = tid; idx < 12 * 64; idx += 256) {
                int j = idx >> 6, mm = idx & 63;
                bondT[(size_t)j * NNP + m0 + mm] = ls[mm * 13 + j];
            }
        }
    }
}

// ============================================================
// gemm1: 64x256 tile, 512 threads (8 waves, each 64r x 32c, acc[4][2]).
// Exps computed ONCE per element (full-N tile) via gaussian recurrence:
// E_{s+1}=E_s*Q_s, Q_{s+1}=Q_s*C. 4-aligned chunks never straddle an
// element boundary (20%4==0, 40%4==0). B: global->frag regs (packed layout
// = frag layout), depth-2 prefetch. A: 4KB LDS ping-pong.
// ============================================================
template <int MODE>  // 0: bond K=480 DIVN=40; 1: angle K=2880 DIVN=20
__device__ __forceinline__ void gemm1_body(const float* __restrict__ xT,
                                           const __bf16* __restrict__ Wp,
                                           float* __restrict__ Y, int mb,
                                           __bf16* __restrict__ Al) {
    constexpr int KTOT = (MODE == 0) ? 480 : 2880;
    constexpr int NKT = KTOT / 32;
    constexpr int DIVN = (MODE == 0) ? 40 : 20;
    constexpr float F0 = (MODE == 0) ? 0.f : -1.f;
    constexpr float FS = (MODE == 0) ? (8.f / 39.f) : (2.f / 19.f);
    constexpr float NG2 = ((MODE == 0) ? -25.f : -100.f) * 1.44269504f;  // -gamma^-2*log2e
    const float C  = __builtin_amdgcn_exp2f(2.f * NG2 * FS * FS);
    const float P1 = NG2 * FS * FS;
    const float P2 = -2.f * NG2 * FS;

    const int tid = threadIdx.x;
    const int lane = tid & 63, wv = tid >> 6;
    const int m0 = mb * 64;
    // staging role: thread -> one 4-element chunk (mt, k8, mi, jh)
    const int smt = tid >> 7;             // 0..3
    const int sk8 = (tid >> 5) & 3;
    const int smi = (tid >> 1) & 15;
    const int sjh = (tid & 1) * 4;
    const int sgm = m0 + smt * 16 + smi;
    const int kk0 = sk8 * 8 + sjh;        // k-offset within tile, 0..28
    const int swoff = (((smt * 4 + sk8) * 16 + smi) * 8 + sjh);
    // MFMA role
    const int k8b = lane >> 4, nib = lane & 15;
    const bf16x8* Bg = (const bf16x8*)Wp;

    f32x4 acc[4][2] = {};
    bf16x8 bcur[2], bnx[2], bnx2[2];

    auto bload = [&](int kt, bf16x8* d) {
#pragma unroll
        for (int jf = 0; jf < 2; ++jf)
            d[jf] = Bg[(((size_t)kt * 16 + 2 * wv + jf) * 4 + k8b) * 16 + nib];
    };
    auto aload = [&](int kt) -> float {
        int k = kt * 32 + kk0;
        int jr = k / DIVN;
        return xT[(size_t)jr * NNP + sgm];
    };
    auto stage = [&](int kt, float a, __bf16* dst) {
        int k = kt * 32 + kk0;
        int jr = k / DIVN;
        int s = k - jr * DIVN;
        float d0 = a - (F0 + (float)s * FS);
        float e0 = __builtin_amdgcn_exp2f(NG2 * d0 * d0);
        float q0 = __builtin_amdgcn_exp2f(fmaf(P2, d0, P1));
        float e1 = e0 * q0;
        float q1 = q0 * C;
        float e2 = e1 * q1;
        float e3 = e2 * q1 * C;
        bf16x4 vals;
        vals[0] = (__bf16)e0; vals[1] = (__bf16)e1;
        vals[2] = (__bf16)e2; vals[3] = (__bf16)e3;
        *(bf16x4*)&dst[swoff] = vals;
    };

    // ---- prologue ----
    {
        float a0 = aload(0);
        stage(0, a0, Al);
    }
    float anext = aload(1 < NKT ? 1 : 0);
    bload(0, bcur);
    bload(1 < NKT ? 1 : 0, bnx);
    __syncthreads();

    for (int kt = 0; kt < NKT; ++kt) {
        __bf16* Ab = Al + ((kt & 1) << 11);
        __bf16* An = Al + (((kt & 1) ^ 1) << 11);
        const int ktp2 = (kt + 2 < NKT) ? kt + 2 : NKT - 1;
        bload(ktp2, bnx2);
        float afut = (kt + 2 < NKT) ? aload(kt + 2) : anext;
        // ---- MFMA on current buffer ----
        bf16x8 af[4];
#pragma unroll
        for (int t = 0; t < 4; ++t)
            af[t] = *(const bf16x8*)&Ab[((((t << 2) + k8b) << 4) + nib) << 3];
#pragma unroll
        for (int i = 0; i < 4; ++i)
#pragma unroll
            for (int j = 0; j < 2; ++j)
                acc[i][j] = __builtin_amdgcn_mfma_f32_16x16x32_bf16(af[i], bcur[j], acc[i][j], 0, 0, 0);
        // ---- stage next tile while matrix pipe drains ----
        if (kt + 1 < NKT)
            stage(kt + 1, anext, An);
        __syncthreads();
#pragma unroll
        for (int j = 0; j < 2; ++j) { bcur[j] = bnx[j]; bnx[j] = bnx2[j]; }
        anext = afut;
    }

    // ---- epilogue: C/D layout col=lane&15, row=(lane>>4)*4+reg; f32 out ----
    const int mrow0 = m0 + ((lane >> 4) << 2);
    const int ncol = (wv << 5) + nib;
#pragma unroll
    for (int i = 0; i < 4; ++i)
#pragma unroll
        for (int j = 0; j < 2; ++j)
#pragma unroll
            for (int v = 0; v < 4; ++v) {
                int m = mrow0 + i * 16 + v;
                if (m < NN) Y[(size_t)m * 256 + ncol + j * 16] = acc[i][j][v];
            }
}

__global__ __launch_bounds__(512, 4) void mega_gemm1(const float* __restrict__ bondT,
                                                     const float* __restrict__ angleT,
                                                     const __bf16* __restrict__ Wp1b,
                                                     const __bf16* __restrict__ Wp1a,
                                                     float* __restrict__ Yb, float* __restrict__ Ya) {
    __shared__ __align__(16) __bf16 Al[2 * 2048];
    int bx = blockIdx.x;
    if (bx < 314) gemm1_body<1>(angleT, Wp1a, Ya, bx, Al);
    else          gemm1_body<0>(bondT, Wp1b, Yb, bx - 314, Al);
}

// ============================================================
// Dense layer-2 GEMM, both chains. K=64, A pre-packed bf16, f32 out
// ============================================================
__global__ __launch_bounds__(256) void mega_gemm2(const __bf16* __restrict__ Hbp,
                                                  const __bf16* __restrict__ Hap,
                                                  const __bf16* __restrict__ Wp2b,
                                                  const __bf16* __restrict__ Wp2a,
                                                  float* __restrict__ Yb, float* __restrict__ Ya) {
    __shared__ __align__(16) __bf16 Al[4096];
    __shared__ __align__(16) __bf16 Bl[4096];
    const int ch = blockIdx.x & 1;
    const int mb = blockIdx.x >> 1;
    const int nb = blockIdx.y;
    const __bf16* Ap = ch ? Hap : Hbp;
    const __bf16* Wp = ch ? Wp2a : Wp2b;
    float* Y = ch ? Ya : Yb;
    const int tid = threadIdx.x;
    const int lane = tid & 63, wv = tid >> 6;
    const int m0 = mb * 128;
    const int rw = wv & 1, cw = wv >> 1;
    f32x4 acc[4][4] = {};
#pragma unroll
    for (int kt = 0; kt < 2; ++kt) {
        __syncthreads();
        {
            const float4* src = (const float4*)(Wp + (((size_t)kt * 16 + nb * 8) << 9));
            float4* dst = (float4*)Bl;
            float4 v0 = src[tid], v1 = src[tid + 256];
            dst[tid] = v0;
            dst[tid + 256] = v1;
        }
        {
            const float4* src = (const float4*)(Ap + (((size_t)kt * MT2 + mb * 8) << 9));
            float4* dst = (float4*)Al;
            float4 v0 = src[tid], v1 = src[tid + 256];
            dst[tid] = v0;
            dst[tid + 256] = v1;
        }
        __syncthreads();
        bf16x8 af[4], bfr[4];
        int fro = ((lane >> 4) << 4) + (lane & 15);
#pragma unroll
        for (int t4 = 0; t4 < 4; ++t4) {
            af[t4] = *(const bf16x8*)&Al[((((rw * 4 + t4) << 6) + fro) << 3)];
            bfr[t4] = *(const bf16x8*)&Bl[((((cw * 4 + t4) << 6) + fro) << 3)];
        }
#pragma unroll
        for (int i = 0; i < 4; ++i)
#pragma unroll
            for (int j = 0; j < 4; ++j)
                acc[i][j] = __builtin_amdgcn_mfma_f32_16x16x32_bf16(af[i], bfr[j], acc[i][j], 0, 0, 0);
    }
    const int n0 = nb * 128 + cw * 64;
    const int mrow0 = m0 + rw * 64 + ((lane >> 4) << 2);
    const int ncol = n0 + (lane & 15);
#pragma unroll
    for (int i = 0; i < 4; ++i)
#pragma unroll
        for (int j = 0; j < 4; ++j)
#pragma unroll
            for (int v = 0; v < 4; ++v) {
                int m = mrow0 + i * 16 + v;
                if (m < NN) Y[(size_t)m * 256 + ncol + j * 16] = acc[i][j][v];
            }
}

// ============================================================
// agg core: scalar (readlane) addresses + 16-batched gathers -> one
// latency wall per batch instead of a serialized shfl chain.
// ============================================================
__device__ __forceinline__ float agg_node(const float* __restrict__ Y,
                                          const int* __restrict__ adj,
                                          const int* __restrict__ deg,
                                          const float* __restrict__ bias,
                                          int node, int h) {
    int dg = min(deg[node], 64);
    int e = adj[(size_t)node * 64 + h];  // lane h holds edge h
    bool val = h < dg;
    int r = e >> 28;
    unsigned long long bl0 = __ballot(val && r == 0);
    unsigned long long bl1 = __ballot(val && r == 1);
    unsigned long long bl2 = __ballot(val && r == 2);
    int c0 = __popcll(bl0), c1 = __popcll(bl1), c2 = __popcll(bl2);
    float s0 = 0.f, s1 = 0.f, s2 = 0.f;
    if (dg > 0) {
        int e0 = __builtin_amdgcn_readfirstlane(e);
        int ec = val ? e : e0;  // clamp garbage lanes to a valid edge
        for (int k0 = 0; k0 < dg; k0 += 16) {
            float v[16];
#pragma unroll
            for (int i = 0; i < 16; ++i) {
                int ek = __builtin_amdgcn_readlane(ec, k0 + i);  // SGPR
                v[i] = Y[(size_t)(ek & 0x0FFFFFFF) * 256 + (ek >> 28) * 64 + h];
            }
#pragma unroll
            for (int i = 0; i < 16; ++i) {
                int kk = k0 + i;
                if (kk < dg) {  // wave-uniform
                    int rr = __builtin_amdgcn_readlane(ec, kk) >> 28;
                    if (rr == 0) s0 += v[i];
                    else if (rr == 1) s1 += v[i];
                    else s2 += v[i];
                }
            }
        }
    }
    float o = Y[(size_t)node * 256 + 192 + h] + bias[h] +
              s0 / fmaxf((float)c0, 1.f) + s1 / fmaxf((float)c1, 1.f) +
              s2 / fmaxf((float)c2, 1.f);
    return fmaxf(o, 0.f);
}

// layer-1 agg -> bf16 packed-A frag layout (feeds mega_gemm2)
__global__ __launch_bounds__(256) void agg_packed(const float* __restrict__ Yb,
                                                  const float* __restrict__ Ya,
                                                  const int* __restrict__ adj,
                                                  const int* __restrict__ deg,
                                                  const float* __restrict__ biasb,
                                                  const float* __restrict__ biasa,
                                                  __bf16* __restrict__ outb,
                                                  __bf16* __restrict__ outa) {
    const float* Y = blockIdx.y ? Ya : Yb;
    const float* bias = blockIdx.y ? biasa : biasb;
    __bf16* outp = blockIdx.y ? outa : outb;
    int node = blockIdx.x * 4 + (threadIdx.x >> 6);
    int h = threadIdx.x & 63;
    float o = (node < NN) ? agg_node(Y, adj, deg, bias, node, h) : 0.f;
    int mt = node >> 4, mi = node & 15;
    int ktt = h >> 5, k8 = (h >> 3) & 3, j = h & 7;
    outp[((((size_t)ktt * MT2 + mt) * 4 + k8) * 16 + mi) * 8 + j] = (__bf16)o;
}

// layer-2 agg fused with crystal pooling
__global__ __launch_bounds__(256) void agg_pool(const float* __restrict__ Yb,
                                                const float* __restrict__ Ya,
                                                const int* __restrict__ adj,
                                                const int* __restrict__ deg,
                                                const float* __restrict__ biasb,
                                                const float* __restrict__ biasa,
                                                const int* __restrict__ crys,
                                                float* __restrict__ pooled) {
    const float* Y = blockIdx.y ? Ya : Yb;
    const float* bias = blockIdx.y ? biasa : biasb;
    const int base = blockIdx.y ? 64 : 0;
    int node = blockIdx.x * 4 + (threadIdx.x >> 6);
    int h = threadIdx.x & 63;
    if (node >= NN) return;
    float o = agg_node(Y, adj, deg, bias, node, h);
    int c = 0;
#pragma unroll
    for (int t = 1; t < NCRYS; ++t) c += (node >= crys[t * 2]) ? 1 : 0;
    int sub = blockIdx.x & (NSUB - 1);
    atomicAdd(&pooled[((size_t)c * NSUB + sub) * 128 + base + h], o);
}

// ============================================================
// final: reduce partials, divide by count, FC
// ============================================================
__global__ void final2(const float* __restrict__ pooled, const int* __restrict__ crys,
                       const float* __restrict__ fcW, const float* __restrict__ fcb,
                       float* __restrict__ out) {
    int c = blockIdx.x >> 1, o = blockIdx.x & 1;
    int l = threadIdx.x;  // 0..63
    float cnt = (float)(crys[c * 2 + 1] - crys[c * 2]);
    float sb = 0.f, sa = 0.f;
    for (int s = 0; s < NSUB; ++s) {
        sb += pooled[((size_t)c * NSUB + s) * 128 + l];
        sa += pooled[((size_t)c * NSUB + s) * 128 + 64 + l];
    }
    float a = sb * fcW[l * 2 + o] + sa * fcW[(64 + l) * 2 + o];
    for (int s = 32; s > 0; s >>= 1) a += __shfl_down(a, s);
    if (l == 0) out[c * 2 + o] = a / cnt + fcb[o];
}

extern "C" void kernel_launch(void* const* d_in, const int* in_sizes, int n_in,
                              void* d_out, int out_size, void* d_ws, size_t ws_size,
                              hipStream_t stream) {
    const float* bond    = (const float*)d_in[0];
    const float* angle   = (const float*)d_in[1];
    const int*   species = (const int*)d_in[2];
    const int*   nbr     = (const int*)d_in[3];
    const int*   crys    = (const int*)d_in[4];
    const float* W1b_rel = (const float*)d_in[5];
    const float* W1b_root= (const float*)d_in[6];
    const float* b1b     = (const float*)d_in[7];
    const float* W1a_rel = (const float*)d_in[8];
    const float* W1a_root= (const float*)d_in[9];
    const float* b1a     = (const float*)d_in[10];
    const float* W2b_rel = (const float*)d_in[11];
    const float* W2b_root= (const float*)d_in[12];
    const float* b2b     = (const float*)d_in[13];
    const float* W2a_rel = (const float*)d_in[14];
    const float* W2a_root= (const float*)d_in[15];
    const float* b2a     = (const float*)d_in[16];
    const float* fcW     = (const float*)d_in[17];
    const float* fcb     = (const float*)d_in[18];
    float* out = (float*)d_out;

    char* ws = (char*)d_ws;
    size_t off = 0;
    auto alloc = [&](size_t bytes) {
        char* p = ws + off;
        off = (off + bytes + 255) & ~(size_t)255;
        return p;
    };
    __bf16* Wp1b = (__bf16*)alloc((size_t)480 * 256 * 2);
    __bf16* Wp1a = (__bf16*)alloc((size_t)2880 * 256 * 2);
    __bf16* Wp2b = (__bf16*)alloc((size_t)64 * 256 * 2);
    __bf16* Wp2a = (__bf16*)alloc((size_t)64 * 256 * 2);
    float*  bondT = (float*)alloc((size_t)12 * NNP * 4);
    float*  angleT= (float*)alloc((size_t)144 * NNP * 4);
    float*  Yb   = (float*)alloc((size_t)NN * 256 * 4);
    float*  Ya   = (float*)alloc((size_t)NN * 256 * 4);
    __bf16* Hbp  = (__bf16*)alloc((size_t)2 * MT2 * 512 * 2);
    __bf16* Hap  = (__bf16*)alloc((size_t)2 * MT2 * 512 * 2);
    int*    adj  = (int*)alloc((size_t)NN * 64 * 4);
    int*    deg  = (int*)alloc((size_t)NN * 4);
    float*  pooled = (float*)alloc((size_t)NCRYS * NSUB * 128 * 4);

    hipMemsetAsync(deg, 0, (size_t)NN * 4, stream);
    hipMemsetAsync(pooled, 0, (size_t)NCRYS * NSUB * 128 * 4, stream);

    setup_kernel<<<1822, 256, 0, stream>>>(species, nbr, adj, deg,
                                           W1b_rel, W1b_root, W1a_rel, W1a_root,
                                           W2b_rel, W2b_root, W2a_rel, W2a_root,
                                           Wp1b, Wp1a, Wp2b, Wp2a,
                                           bond, angle, bondT, angleT);

    mega_gemm1<<<628, 512, 0, stream>>>(bondT, angleT, Wp1b, Wp1a, Yb, Ya);
    agg_packed<<<dim3(5024, 2), 256, 0, stream>>>(Yb, Ya, adj, deg, b1b, b1a, Hbp, Hap);
    mega_gemm2<<<dim3(314, 2), 256, 0, stream>>>(Hbp, Hap, Wp2b, Wp2a, Yb, Ya);
    agg_pool<<<dim3(5000, 2), 256, 0, stream>>>(Yb, Ya, adj, deg, b2b, b2a, crys, pooled);
    final2<<<NCRYS * 2, 64, 0, stream>>>(pooled, crys, fcW, fcb, out);
}